// Round 19
// baseline (187.553 us; speedup 1.0000x reference)
//
#include <hip/hip_runtime.h>
#include <stdint.h>

typedef __attribute__((ext_vector_type(4))) float f32x4;
typedef __attribute__((ext_vector_type(8))) short short8_t;     // 8 bf16 for MFMA operand
typedef __attribute__((ext_vector_type(8))) unsigned short ushort8_t;

__device__ __forceinline__ unsigned short f2bf(float f) {
    unsigned int u = __builtin_bit_cast(unsigned int, f);
    u = (u + 0x7fffu + ((u >> 16) & 1u)) >> 16;   // round-to-nearest-even
    return (unsigned short)u;
}
__device__ __forceinline__ float bf2f(unsigned short h) {
    unsigned int u = ((unsigned int)h) << 16;
    return __builtin_bit_cast(float, u);
}

// async global->LDS, 16B per lane. LDS dest = wave-uniform base + lane*16.
__device__ __forceinline__ void gll16(const unsigned short* g, unsigned short* l) {
    __builtin_amdgcn_global_load_lds(
        (const __attribute__((address_space(1))) void*)g,
        (__attribute__((address_space(3))) void*)l, 16, 0, 0);
}

// ---------------------------------------------------------------- prep weights
__global__ __launch_bounds__(256) void prep_w(
    const float* __restrict__ g_w, const float* __restrict__ W_w,
    const float* __restrict__ W_b, const float* __restrict__ gamma,
    const float* __restrict__ beta, const float* __restrict__ mean,
    const float* __restrict__ var,
    unsigned short* __restrict__ gwb, unsigned short* __restrict__ wwb,
    float* __restrict__ bnA, float* __restrict__ bnB)
{
    int i = blockIdx.x * 256 + threadIdx.x;
    if (i < 256 * 512) { gwb[i] = f2bf(g_w[i]); wwb[i] = f2bf(W_w[i]); }
    if (i < 512) {
        float is = rsqrtf(var[i] + 1e-5f);
        float a = gamma[i] * is;
        bnA[i] = a;
        bnB[i] = (W_b[i] - mean[i]) * a + beta[i];
    }
}

// ---------------- fused Q+K build: read x once (float4), write Q^T / pooled K^T
// as ushort8 (16B coalesced stores).  Block: 32 ch x 128 pos.  grid (32,16,8).
__global__ __launch_bounds__(256) void build_qk(
    const float* __restrict__ x, unsigned short* __restrict__ Qh,
    unsigned short* __restrict__ Kh)
{
    __shared__ float t[32][129];   // +1 pad; stride 129 ≡ 1 mod 32 (2-way max)
    int b = blockIdx.z;
    int p0 = blockIdx.x * 128, c0 = blockIdx.y * 32;
    const float* xb = x + (long)b * 512 * 4096;
    int tid = threadIdx.x;
    for (int i = 0; i < 4; i++) {
        int f4 = i * 256 + tid;            // 0..1023 float4s
        int c = f4 >> 5, p4 = (f4 & 31) * 4;
        float4 v = *(const float4*)(xb + (long)(c0 + c) * 4096 + p0 + p4);
        t[c][p4] = v.x; t[c][p4 + 1] = v.y; t[c][p4 + 2] = v.z; t[c][p4 + 3] = v.w;
    }
    __syncthreads();
    unsigned short* qb = Qh + (long)b * 4096 * 512;
    for (int i = 0; i < 2; i++) {
        int u = i * 256 + tid;             // 0..511
        int p = u >> 2, cg = (u & 3) * 8;
        ushort8_t o;
        for (int e = 0; e < 8; e++) o[e] = f2bf(t[cg + e][p]);
        *(ushort8_t*)(qb + (long)(p0 + p) * 512 + c0 + cg) = o;
    }
    unsigned short* kb = Kh + (long)b * 1024 * 512;
    int kp0 = p0 >> 2;   // pooled row base
    if (tid < 128) {
        int w = tid >> 2, cg = (tid & 3) * 8;
        ushort8_t o;
        for (int e = 0; e < 8; e++) {
            int c = cg + e;
            float v = fmaxf(fmaxf(t[c][2 * w], t[c][2 * w + 1]),
                            fmaxf(t[c][64 + 2 * w], t[c][64 + 2 * w + 1]));
            o[e] = f2bf(v);
        }
        *(ushort8_t*)(kb + (long)(kp0 + w) * 512 + c0 + cg) = o;
    }
}

// ---------------- V build: Gp[ci][k'] = bf16(g_b[ci] + maxpool2(Gt)[ci][k'])
__global__ __launch_bounds__(256) void build_v(
    const unsigned short* __restrict__ Gt, const float* __restrict__ g_b,
    unsigned short* __restrict__ Gp)
{
    int b = blockIdx.z;
    int k  = blockIdx.x * 32 + (threadIdx.x & 31);
    int ci = blockIdx.y * 8 + (threadIdx.x >> 5);
    int h = k >> 5, w = k & 31;
    const unsigned short* g = Gt + (long)b * 4096 * 256;
    long p = (long)(h * 128 + w * 2) * 256 + ci;
    float v0 = bf2f(g[p]),        v1 = bf2f(g[p + 256]);
    float v2 = bf2f(g[p + 64*256]), v3 = bf2f(g[p + 65*256]);
    float v = fmaxf(fmaxf(v0, v1), fmaxf(v2, v3)) + g_b[ci];
    Gp[(long)b * 256 * 1024 + (long)ci * 1024 + k] = f2bf(v);
}

// ------------------------------------------- fused ONLINE softmax + PV
// Per block: 64 q-rows, 1024 keys, 256 ci.  No pre-scan: flash-style running
// max per row (4 threads/row compute tile max from prefetched S regs; quad
// leader publishes scale=exp(m_old-m_new) via LDS; accs rescaled post-barrier
// before MFMA).  p = exp(s - m_run) unnormalized; psum carries the same
// cumulative scale; 1/psum applied in epilogue.
__global__ __launch_bounds__(256) void pv_fused(
    const unsigned short* __restrict__ S, long sbstr,
    const unsigned short* __restrict__ Gp, long gbstr,
    unsigned short* __restrict__ Y, long ybstr)
{
    __shared__ unsigned short lV[256 * 64];   // 32 KB
    __shared__ unsigned short lP[64 * 64];    // 8 KB
    __shared__ float lscale[64];
    __shared__ float li[64];

    const int tid = threadIdx.x;
    const int wid = tid >> 6, lane = tid & 63;

    // XCD-aware remap
    unsigned gx = gridDim.x, gy = gridDim.y;
    unsigned nwg = gx * gy;
    unsigned lin = blockIdx.x + gx * blockIdx.y;
    unsigned l = ((nwg & 7u) == 0u) ? ((lin & 7u) * (nwg >> 3) + (lin >> 3)) : lin;
    unsigned bx = l % gx, by = l / gx;

    const int q0 = (int)bx * 64;
    const unsigned short* Sb = S + by * sbstr + (long)q0 * 1024;
    const unsigned short* Gb = Gp + by * gbstr;
    unsigned short* Yb = Y + by * ybstr + (long)q0 * 256;

    const int wr = wid >> 1, wc = wid & 1;
    const int lr = lane & 15, lg = lane >> 4;
    const int srA = lane >> 3;
    const int scg = (((lane & 7) ^ srA) << 3);
    const int pr = tid >> 2;            // lP row 0..63 (this thread's softmax row)
    const int pc = (tid & 3) * 2;       // chunk base (2 chunks of 8 keys)

    f32x4 acc[2][8];
    for (int mi = 0; mi < 2; mi++)
        for (int ni = 0; ni < 8; ni++)
            acc[mi][ni] = (f32x4){0.f, 0.f, 0.f, 0.f};
    float psum = 0.f;                   // quarter-row sum (cumulative-scaled)
    float m_run = -3.0e38f;             // running row max

    // S register pipeline: s0 = chunk for current kb (loaded one iter ahead)
    const unsigned short* sprow = Sb + (long)pr * 1024 + pc * 8;
    ushort8_t s0a = *(const ushort8_t*)sprow;
    ushort8_t s0b = *(const ushort8_t*)(sprow + 8);

    for (int kb = 0; kb < 16; kb++) {
        __syncthreads();   // prev MFMA reads + lscale reads done
        // stage V tile [256 ci][64 keys] (linear LDS dest, pre-swizzled source)
        for (int i = 0; i < 8; i++) {
            int cibase = i * 32 + wid * 8;
            gll16(Gb + (long)(cibase + srA) * 1024 + kb * 64 + scg, &lV[cibase * 64]);
        }
        // prefetch NEXT S chunk to regs
        int kn = (kb < 15) ? kb + 1 : 15;
        const unsigned short* spn = sprow + kn * 64;
        ushort8_t s1a = *(const ushort8_t*)spn;
        ushort8_t s1b = *(const ushort8_t*)(spn + 8);
        // online max for this tile (from already-resident regs)
        float f0[8], f1[8];
        float cm = -3.0e38f;
        for (int e = 0; e < 8; e++) {
            f0[e] = bf2f(s0a[e]); f1[e] = bf2f(s0b[e]);
            cm = fmaxf(cm, fmaxf(f0[e], f1[e]));
        }
        cm = fmaxf(cm, __shfl_xor(cm, 1));
        cm = fmaxf(cm, __shfl_xor(cm, 2));   // row-tile max (4-thread quad)
        float m_new = fmaxf(m_run, cm);
        float sc = __expf(m_run - m_new);    // 0 on first tile, 1 if no change
        if ((tid & 3) == 0) lscale[pr] = sc;
        psum *= sc;
        m_run = m_new;
        // exp -> lP (XOR chunk swizzle); overlaps V DMA
        {
            ushort8_t o8;
            for (int e = 0; e < 8; e++) {
                float pe = __expf(f0[e] - m_run);
                psum += pe;
                o8[e] = f2bf(pe);
            }
            *(ushort8_t*)(&lP[pr * 64 + ((pc ^ (pr & 7)) * 8)]) = o8;
            for (int e = 0; e < 8; e++) {
                float pe = __expf(f1[e] - m_run);
                psum += pe;
                o8[e] = f2bf(pe);
            }
            *(ushort8_t*)(&lP[pr * 64 + (((pc + 1) ^ (pr & 7)) * 8)]) = o8;
        }
        __syncthreads();   // drains vmcnt(0) + lP/lscale visible
        // rescale accumulators by their OUTPUT row's scale, then MFMA
        for (int mi = 0; mi < 2; mi++) {
            int rbase = wr * 32 + mi * 16 + lg * 4;
            f32x4 rs;
            rs[0] = lscale[rbase];     rs[1] = lscale[rbase + 1];
            rs[2] = lscale[rbase + 2]; rs[3] = lscale[rbase + 3];
            for (int ni = 0; ni < 8; ni++)
                acc[mi][ni] *= rs;
        }
        for (int ks = 0; ks < 2; ks++) {
            short8_t af[2], bfr[8];
            for (int mi = 0; mi < 2; mi++) {
                int row = wr * 32 + mi * 16 + lr;
                int ch = ((ks * 4 + lg) ^ (row & 7)) * 8;
                af[mi] = *(const short8_t*)(&lP[row * 64 + ch]);
            }
            for (int ni = 0; ni < 8; ni++) {
                int row = wc * 128 + ni * 16 + lr;
                int ch = ((ks * 4 + lg) ^ (row & 7)) * 8;
                bfr[ni] = *(const short8_t*)(&lV[row * 64 + ch]);
            }
            for (int mi = 0; mi < 2; mi++)
                for (int ni = 0; ni < 8; ni++)
                    acc[mi][ni] = __builtin_amdgcn_mfma_f32_16x16x32_bf16(
                        af[mi], bfr[ni], acc[mi][ni], 0, 0, 0);
        }
        s0a = s1a; s0b = s1b;
    }

    // reduce 4 partial sums per row -> li
    psum += __shfl_xor(psum, 1);
    psum += __shfl_xor(psum, 2);
    if ((tid & 3) == 0) li[pr] = 1.0f / psum;
    __syncthreads();

    // epilogue: Y[row][ci] = bf16(acc * 1/l)
    for (int mi = 0; mi < 2; mi++) {
        for (int ni = 0; ni < 8; ni++) {
            int ci = wc * 128 + ni * 16 + lr;
            int rbase = wr * 32 + mi * 16 + lg * 4;
            for (int r = 0; r < 4; r++) {
                int row = rbase + r;
                Yb[(long)row * 256 + ci] = f2bf(acc[mi][ni][r] * li[row]);
            }
        }
    }
}

// -------------------- fused QK^T + G-conv GEMM (shares A=Qh, K=512)
// grid (10, 32, G): bx<8 -> C=S tile (B=Kh_z);  bx>=8 -> C=Gt tile (B=gwb).
// Direct scalar-store epilogue (LDS-transposed variant measured slower).
__global__ __launch_bounds__(256) void gemm_qkg(
    const unsigned short* __restrict__ Qh,
    const unsigned short* __restrict__ Kh,
    const unsigned short* __restrict__ gwb,
    unsigned short* __restrict__ S,
    unsigned short* __restrict__ Gt)
{
    __shared__ unsigned short lA[128 * 64];
    __shared__ unsigned short lB[128 * 64];
    const int tid = threadIdx.x;
    const int wid = tid >> 6, lane = tid & 63;

    unsigned gx = gridDim.x, gy = gridDim.y;
    unsigned nwg = gx * gy * gridDim.z;
    unsigned lin = blockIdx.x + gx * (blockIdx.y + gy * blockIdx.z);
    unsigned l = ((nwg & 7u) == 0u) ? ((lin & 7u) * (nwg >> 3) + (lin >> 3)) : lin;
    unsigned bx = l % gx;
    unsigned rem = l / gx;
    unsigned by = rem % gy;
    unsigned bz = rem / gy;

    const int z = (int)bz;
    const int m0 = (int)by * 128;
    const unsigned short* Ab = Qh + (long)z * 4096 * 512;
    const unsigned short* Bb;
    unsigned short* Cb;
    int n0, ldc;
    if (bx < 8) {
        Bb = Kh + (long)z * 1024 * 512;  n0 = bx * 128;
        Cb = S + (long)z * 4096 * 1024;  ldc = 1024;
    } else {
        Bb = gwb;                         n0 = (bx - 8) * 128;
        Cb = Gt + (long)z * 4096 * 256;   ldc = 256;
    }

    const int wr = wid >> 1, wc = wid & 1;
    const int lr = lane & 15, lg = lane >> 4;
    const int srA = lane >> 3;
    const int scg = (((lane & 7) ^ srA) << 3);

    f32x4 acc[4][4];
    for (int mi = 0; mi < 4; mi++)
        for (int ni = 0; ni < 4; ni++)
            acc[mi][ni] = (f32x4){0.f, 0.f, 0.f, 0.f};

    for (int k0 = 0; k0 < 512; k0 += 64) {
        __syncthreads();
        for (int i = 0; i < 4; i++) {
            int rowbase = i * 32 + wid * 8;
            gll16(Ab + (long)(m0 + rowbase + srA) * 512 + k0 + scg, &lA[rowbase * 64]);
            gll16(Bb + (long)(n0 + rowbase + srA) * 512 + k0 + scg, &lB[rowbase * 64]);
        }
        __syncthreads();
        for (int kk = 0; kk < 2; kk++) {
            short8_t af[4], bfr[4];
            for (int mi = 0; mi < 4; mi++) {
                int row = wr * 64 + mi * 16 + lr;
                int ch = ((kk * 4 + lg) ^ (row & 7)) * 8;
                af[mi] = *(const short8_t*)(&lA[row * 64 + ch]);
            }
            for (int ni = 0; ni < 4; ni++) {
                int row = wc * 64 + ni * 16 + lr;
                int ch = ((kk * 4 + lg) ^ (row & 7)) * 8;
                bfr[ni] = *(const short8_t*)(&lB[row * 64 + ch]);
            }
            for (int mi = 0; mi < 4; mi++)
                for (int ni = 0; ni < 4; ni++)
                    acc[mi][ni] = __builtin_amdgcn_mfma_f32_16x16x32_bf16(
                        af[mi], bfr[ni], acc[mi][ni], 0, 0, 0);
        }
    }

    for (int mi = 0; mi < 4; mi++) {
        for (int ni = 0; ni < 4; ni++) {
            int ncol = n0 + wc * 64 + ni * 16 + lr;
            int mrow = m0 + wr * 64 + mi * 16 + lg * 4;
            for (int r = 0; r < 4; r++) {
                Cb[(long)(mrow + r) * ldc + ncol] = f2bf(acc[mi][ni][r]);
            }
        }
    }
}

// -------------------------------------------------------------------- GEMM
// EPI: 0 f32 store, 1 bf16 store, 2 v*bnA[m]+bnB[m]+Xres f32 store.
template<int EPI>
__global__ __launch_bounds__(256) void gemm_abt(
    const unsigned short* __restrict__ A, int lda, long abstr,
    const unsigned short* __restrict__ B, int ldb, long bbstr,
    void* __restrict__ Cv, int ldc, long cbstr,
    int K,
    const float* __restrict__ bnA, const float* __restrict__ bnB,
    const float* __restrict__ Xres, long xbstr)
{
    __shared__ unsigned short lA[128 * 64];
    __shared__ unsigned short lB[128 * 64];
    const int tid = threadIdx.x;
    const int wid = tid >> 6, lane = tid & 63;

    unsigned gx = gridDim.x, gy = gridDim.y;
    unsigned nwg = gx * gy * gridDim.z;
    unsigned lin = blockIdx.x + gx * (blockIdx.y + gy * blockIdx.z);
    unsigned l = ((nwg & 7u) == 0u) ? ((lin & 7u) * (nwg >> 3) + (lin >> 3)) : lin;
    unsigned bx = l % gx;
    unsigned rem = l / gx;
    unsigned by = rem % gy;
    unsigned bz = rem / gy;

    const int z = (int)bz;
    const int m0 = (int)by * 128, n0 = (int)bx * 128;
    const unsigned short* Ab = A + z * abstr;
    const unsigned short* Bb = B + z * bbstr;
    const int wr = wid >> 1, wc = wid & 1;
    const int lr = lane & 15, lg = lane >> 4;

    const int srA = lane >> 3;
    const int scg = (((lane & 7) ^ srA) << 3);

    f32x4 acc[4][4];
    for (int mi = 0; mi < 4; mi++)
        for (int ni = 0; ni < 4; ni++)
            acc[mi][ni] = (f32x4){0.f, 0.f, 0.f, 0.f};

    for (int k0 = 0; k0 < K; k0 += 64) {
        __syncthreads();
        for (int i = 0; i < 4; i++) {
            int rowbase = i * 32 + wid * 8;
            gll16(Ab + (long)(m0 + rowbase + srA) * lda + k0 + scg, &lA[rowbase * 64]);
            gll16(Bb + (long)(n0 + rowbase + srA) * ldb + k0 + scg, &lB[rowbase * 64]);
        }
        __syncthreads();
        for (int kk = 0; kk < 2; kk++) {
            short8_t af[4], bfr[4];
            for (int mi = 0; mi < 4; mi++) {
                int row = wr * 64 + mi * 16 + lr;
                int ch = ((kk * 4 + lg) ^ (row & 7)) * 8;
                af[mi] = *(const short8_t*)(&lA[row * 64 + ch]);
            }
            for (int ni = 0; ni < 4; ni++) {
                int row = wc * 64 + ni * 16 + lr;
                int ch = ((kk * 4 + lg) ^ (row & 7)) * 8;
                bfr[ni] = *(const short8_t*)(&lB[row * 64 + ch]);
            }
            for (int mi = 0; mi < 4; mi++)
                for (int ni = 0; ni < 4; ni++)
                    acc[mi][ni] = __builtin_amdgcn_mfma_f32_16x16x32_bf16(
                        af[mi], bfr[ni], acc[mi][ni], 0, 0, 0);
        }
    }

    for (int mi = 0; mi < 4; mi++) {
        for (int ni = 0; ni < 4; ni++) {
            int ncol = n0 + wc * 64 + ni * 16 + lr;
            int mrow = m0 + wr * 64 + mi * 16 + lg * 4;
            for (int r = 0; r < 4; r++) {
                int row = mrow + r;
                float v = acc[mi][ni][r];
                long idx = z * cbstr + (long)row * ldc + ncol;
                if (EPI == 0) {
                    ((float*)Cv)[idx] = v;
                } else if (EPI == 1) {
                    ((unsigned short*)Cv)[idx] = f2bf(v);
                } else {
                    float o = v * bnA[row] + bnB[row] + Xres[z * xbstr + (long)row * ldc + ncol];
                    ((float*)Cv)[idx] = o;
                }
            }
        }
    }
}

// fallback if workspace too small (diagnostic: out = x)
__global__ void copy_residual(const float* __restrict__ x, float* __restrict__ out, long n)
{
    for (long i = blockIdx.x * 256ll + threadIdx.x; i < n; i += (long)gridDim.x * 256)
        out[i] = x[i];
}

extern "C" void kernel_launch(void* const* d_in, const int* in_sizes, int n_in,
                              void* d_out, int out_size, void* d_ws, size_t ws_size,
                              hipStream_t stream)
{
    const float* x     = (const float*)d_in[0];
    const float* g_w   = (const float*)d_in[1];
    const float* g_b   = (const float*)d_in[2];
    const float* W_w   = (const float*)d_in[3];
    const float* W_b   = (const float*)d_in[4];
    const float* gamma = (const float*)d_in[5];
    const float* beta  = (const float*)d_in[6];
    const float* mean  = (const float*)d_in[7];
    const float* var   = (const float*)d_in[8];
    float* out = (float*)d_out;

    char* ws = (char*)d_ws;
    size_t o = 0;
    auto alloc = [&](size_t bytes) { size_t r = o; o = (o + bytes + 255) & ~(size_t)255; return r; };
    size_t o_gwb = alloc(256 * 512 * 2);
    size_t o_wwb = alloc(512 * 256 * 2);
    size_t o_bnA = alloc(512 * 4);
    size_t o_bnB = alloc(512 * 4);
    size_t o_q   = alloc(8ull * 4096 * 512 * 2);   // Qh bf16
    size_t o_k   = alloc(8ull * 1024 * 512 * 2);   // Kh bf16
    size_t o_gp  = alloc(8ull * 256 * 1024 * 2);   // V^T (pooled g, bf16)
    size_t o_y   = alloc(8ull * 4096 * 256 * 2);   // Y (also holds Gt before pooling)
    size_t o_s   = o;                               // S bf16 logits
    const size_t srow_bytes = 1024ull * 2;          // one S row (bf16)
    const size_t sb1 = 4096ull * srow_bytes;        // one batch of S (8 MB)

    int G = 0, RC = 0;
    if      (o_s + 8 * sb1 <= ws_size) G = 8;
    else if (o_s + 4 * sb1 <= ws_size) G = 4;
    else if (o_s + 2 * sb1 <= ws_size) G = 2;
    else if (o_s + 1 * sb1 <= ws_size) G = 1;
    else {
        for (int rc = 2048; rc >= 128; rc >>= 1)
            if (o_s + (size_t)rc * srow_bytes <= ws_size) { RC = rc; break; }
        if (!RC) {
            copy_residual<<<dim3(2048), dim3(256), 0, stream>>>(x, out, (long)out_size);
            return;
        }
    }

    unsigned short* gwb = (unsigned short*)(ws + o_gwb);
    unsigned short* wwb = (unsigned short*)(ws + o_wwb);
    float* bnA = (float*)(ws + o_bnA);
    float* bnB = (float*)(ws + o_bnB);
    unsigned short* Qh  = (unsigned short*)(ws + o_q);
    unsigned short* Kh  = (unsigned short*)(ws + o_k);
    unsigned short* Gp  = (unsigned short*)(ws + o_gp);
    unsigned short* Y   = (unsigned short*)(ws + o_y);
    unsigned short* S   = (unsigned short*)(ws + o_s);

    prep_w<<<dim3(512), dim3(256), 0, stream>>>(g_w, W_w, W_b, gamma, beta, mean, var,
                                                gwb, wwb, bnA, bnB);
    build_qk<<<dim3(32, 16, 8), dim3(256), 0, stream>>>(x, Qh, Kh);

    if (G) {
        for (int bg = 0; bg < 8; bg += G) {
            // fused QK^T + G-conv (shared A panels): S and Gt (into Y slot)
            gemm_qkg<<<dim3(10, 32, G), dim3(256), 0, stream>>>(
                Qh + (size_t)bg * 4096 * 512,
                Kh + (size_t)bg * 1024 * 512,
                gwb,
                S,
                Y + (size_t)bg * 4096 * 256);
            build_v<<<dim3(32, 32, G), dim3(256), 0, stream>>>(
                Y + (size_t)bg * 4096 * 256, g_b, Gp + (size_t)bg * 256 * 1024);
            // fused online softmax + PV (deferred normalization)
            pv_fused<<<dim3(64, G), dim3(256), 0, stream>>>(
                S, 4096l * 1024,
                Gp + (size_t)bg * 256 * 1024, 256l * 1024,
                Y + (size_t)bg * 4096 * 256, 4096l * 256);
        }
    } else {
        // Row-chunked path (small workspace): separate G-conv first, then chunks.
        gemm_abt<1><<<dim3(2, 32, 8), dim3(256), 0, stream>>>(
            Qh, 512, 4096l * 512,
            gwb, 512, 0,
            (void*)Y, 256, 4096l * 256, 512,
            nullptr, nullptr, nullptr, 0);
        build_v<<<dim3(32, 32, 8), dim3(256), 0, stream>>>(Y, g_b, Gp);
        for (int b = 0; b < 8; b++) {
            for (int r0 = 0; r0 < 4096; r0 += RC) {
                const unsigned short* Aq = Qh + (size_t)b * 4096 * 512 + (size_t)r0 * 512;
                gemm_abt<1><<<dim3(8, RC / 128, 1), dim3(256), 0, stream>>>(
                    Aq, 512, 0,
                    Kh + (size_t)b * 1024 * 512, 512, 0,
                    (void*)S, 1024, 0, 512,
                    nullptr, nullptr, nullptr, 0);
                pv_fused<<<dim3(RC / 64, 1), dim3(256), 0, stream>>>(
                    S, 0,
                    Gp + (size_t)b * 256 * 1024, 0,
                    Y + ((size_t)b * 4096 + r0) * 256, 0);
            }
        }
    }

    // W-conv + BN + residual: out[b][o][p] = (wwb·Y^T)*bnA[o]+bnB[o]+x  (M=512,N=4096,K=256)
    gemm_abt<2><<<dim3(32, 4, 8), dim3(256), 0, stream>>>(
        wwb, 256, 0,
        Y, 256, 4096l * 256,
        (void*)out, 4096, 512l * 4096, 256,
        bnA, bnB, x, 512l * 4096);
}

// Round 20
// 170.834 us; speedup vs baseline: 1.0979x; 1.0979x over previous
//
#include <hip/hip_runtime.h>
#include <stdint.h>

typedef __attribute__((ext_vector_type(4))) float f32x4;
typedef __attribute__((ext_vector_type(8))) short short8_t;     // 8 bf16 for MFMA operand
typedef __attribute__((ext_vector_type(8))) unsigned short ushort8_t;

__device__ __forceinline__ unsigned short f2bf(float f) {
    unsigned int u = __builtin_bit_cast(unsigned int, f);
    u = (u + 0x7fffu + ((u >> 16) & 1u)) >> 16;   // round-to-nearest-even
    return (unsigned short)u;
}
__device__ __forceinline__ float bf2f(unsigned short h) {
    unsigned int u = ((unsigned int)h) << 16;
    return __builtin_bit_cast(float, u);
}

// async global->LDS, 16B per lane. LDS dest = wave-uniform base + lane*16.
__device__ __forceinline__ void gll16(const unsigned short* g, unsigned short* l) {
    __builtin_amdgcn_global_load_lds(
        (const __attribute__((address_space(1))) void*)g,
        (__attribute__((address_space(3))) void*)l, 16, 0, 0);
}

// ---------------------------------------------------------------- prep weights
__global__ __launch_bounds__(256) void prep_w(
    const float* __restrict__ g_w, const float* __restrict__ W_w,
    const float* __restrict__ W_b, const float* __restrict__ gamma,
    const float* __restrict__ beta, const float* __restrict__ mean,
    const float* __restrict__ var,
    unsigned short* __restrict__ gwb, unsigned short* __restrict__ wwb,
    float* __restrict__ bnA, float* __restrict__ bnB)
{
    int i = blockIdx.x * 256 + threadIdx.x;
    if (i < 256 * 512) { gwb[i] = f2bf(g_w[i]); wwb[i] = f2bf(W_w[i]); }
    if (i < 512) {
        float is = rsqrtf(var[i] + 1e-5f);
        float a = gamma[i] * is;
        bnA[i] = a;
        bnB[i] = (W_b[i] - mean[i]) * a + beta[i];
    }
}

// ---------------- fused Q+K build: read x once (float4), write Q^T / pooled K^T
// as ushort8 (16B coalesced stores).  Block: 32 ch x 128 pos.  grid (32,16,8).
__global__ __launch_bounds__(256) void build_qk(
    const float* __restrict__ x, unsigned short* __restrict__ Qh,
    unsigned short* __restrict__ Kh)
{
    __shared__ float t[32][129];   // +1 pad; stride 129 ≡ 1 mod 32 (2-way max)
    int b = blockIdx.z;
    int p0 = blockIdx.x * 128, c0 = blockIdx.y * 32;
    const float* xb = x + (long)b * 512 * 4096;
    int tid = threadIdx.x;
    for (int i = 0; i < 4; i++) {
        int f4 = i * 256 + tid;            // 0..1023 float4s
        int c = f4 >> 5, p4 = (f4 & 31) * 4;
        float4 v = *(const float4*)(xb + (long)(c0 + c) * 4096 + p0 + p4);
        t[c][p4] = v.x; t[c][p4 + 1] = v.y; t[c][p4 + 2] = v.z; t[c][p4 + 3] = v.w;
    }
    __syncthreads();
    unsigned short* qb = Qh + (long)b * 4096 * 512;
    for (int i = 0; i < 2; i++) {
        int u = i * 256 + tid;             // 0..511
        int p = u >> 2, cg = (u & 3) * 8;
        ushort8_t o;
        for (int e = 0; e < 8; e++) o[e] = f2bf(t[cg + e][p]);
        *(ushort8_t*)(qb + (long)(p0 + p) * 512 + c0 + cg) = o;
    }
    unsigned short* kb = Kh + (long)b * 1024 * 512;
    int kp0 = p0 >> 2;   // pooled row base
    if (tid < 128) {
        int w = tid >> 2, cg = (tid & 3) * 8;
        ushort8_t o;
        for (int e = 0; e < 8; e++) {
            int c = cg + e;
            float v = fmaxf(fmaxf(t[c][2 * w], t[c][2 * w + 1]),
                            fmaxf(t[c][64 + 2 * w], t[c][64 + 2 * w + 1]));
            o[e] = f2bf(v);
        }
        *(ushort8_t*)(kb + (long)(kp0 + w) * 512 + c0 + cg) = o;
    }
}

// ---------------- V build: Gp[ci][k'] = bf16(g_b[ci] + maxpool2(Gt)[ci][k'])
__global__ __launch_bounds__(256) void build_v(
    const unsigned short* __restrict__ Gt, const float* __restrict__ g_b,
    unsigned short* __restrict__ Gp)
{
    int b = blockIdx.z;
    int k  = blockIdx.x * 32 + (threadIdx.x & 31);
    int ci = blockIdx.y * 8 + (threadIdx.x >> 5);
    int h = k >> 5, w = k & 31;
    const unsigned short* g = Gt + (long)b * 4096 * 256;
    long p = (long)(h * 128 + w * 2) * 256 + ci;
    float v0 = bf2f(g[p]),        v1 = bf2f(g[p + 256]);
    float v2 = bf2f(g[p + 64*256]), v3 = bf2f(g[p + 65*256]);
    float v = fmaxf(fmaxf(v0, v1), fmaxf(v2, v3)) + g_b[ci];
    Gp[(long)b * 256 * 1024 + (long)ci * 1024 + k] = f2bf(v);
}

// ------------------------------------------- fused scan + softmax + PV
// Per block: 64 q-rows, 1024 keys, 256 ci.
// Phase 0: wave-coalesced row-max scan -> lm (pulls S slice into L2).
// Main: per 64-key block, S[kb+1] prefetched to REGISTERS during iter kb
// (exp never waits on S); V tile via gll16; p=exp(s-m) unnormalized -> bf16 ->
// MFMA; psum alongside; 1/l in epilogue.
__global__ __launch_bounds__(256) void pv_fused(
    const unsigned short* __restrict__ S, long sbstr,
    const unsigned short* __restrict__ Gp, long gbstr,
    unsigned short* __restrict__ Y, long ybstr)
{
    __shared__ unsigned short lV[256 * 64];   // 32 KB
    __shared__ unsigned short lP[64 * 64];    // 8 KB
    __shared__ float lm[64], li[64];

    const int tid = threadIdx.x;
    const int wid = tid >> 6, lane = tid & 63;

    // XCD-aware remap
    unsigned gx = gridDim.x, gy = gridDim.y;
    unsigned nwg = gx * gy;
    unsigned lin = blockIdx.x + gx * blockIdx.y;
    unsigned l = ((nwg & 7u) == 0u) ? ((lin & 7u) * (nwg >> 3) + (lin >> 3)) : lin;
    unsigned bx = l % gx, by = l / gx;

    const int q0 = (int)bx * 64;
    const unsigned short* Sb = S + by * sbstr + (long)q0 * 1024;
    const unsigned short* Gb = Gp + by * gbstr;
    unsigned short* Yb = Y + by * ybstr + (long)q0 * 256;

    // ---- phase 0: coalesced row-max scan (wave-parallel)
    for (int rr = 0; rr < 16; rr++) {
        int r = (wid << 4) + rr;
        const unsigned short* pS = Sb + (long)r * 1024 + lane * 16;
        ushort8_t v0 = *(const ushort8_t*)pS;
        ushort8_t v1 = *(const ushort8_t*)(pS + 8);
        float m = -3.0e38f;
        for (int e = 0; e < 8; e++)
            m = fmaxf(m, fmaxf(bf2f(v0[e]), bf2f(v1[e])));
        for (int off = 32; off; off >>= 1) m = fmaxf(m, __shfl_xor(m, off));
        if (lane == 0) lm[r] = m;
    }
    __syncthreads();

    const int wr = wid >> 1, wc = wid & 1;
    const int lr = lane & 15, lg = lane >> 4;
    const int srA = lane >> 3;
    const int scg = (((lane & 7) ^ srA) << 3);
    const int pr = tid >> 2;            // lP row 0..63
    const int pc = (tid & 3) * 2;       // chunk base (2 chunks of 8 keys)

    const float m = lm[pr];             // exact row max (f32)

    f32x4 acc[2][8];
    for (int mi = 0; mi < 2; mi++)
        for (int ni = 0; ni < 8; ni++)
            acc[mi][ni] = (f32x4){0.f, 0.f, 0.f, 0.f};
    float psum = 0.f;                   // this thread's quarter-row sum of p

    // S register pipeline: s0 = chunk for current kb (loaded one iter ahead)
    const unsigned short* sprow = Sb + (long)pr * 1024 + pc * 8;
    ushort8_t s0a = *(const ushort8_t*)sprow;
    ushort8_t s0b = *(const ushort8_t*)(sprow + 8);

    for (int kb = 0; kb < 16; kb++) {
        __syncthreads();   // prev MFMA reads done
        // stage V tile [256 ci][64 keys] (linear LDS dest, pre-swizzled source)
        for (int i = 0; i < 8; i++) {
            int cibase = i * 32 + wid * 8;
            gll16(Gb + (long)(cibase + srA) * 1024 + kb * 64 + scg, &lV[cibase * 64]);
        }
        // prefetch NEXT S chunk to regs (consumed next iteration; L2-hot)
        int kn = (kb < 15) ? kb + 1 : 15;
        const unsigned short* spn = sprow + kn * 64;
        ushort8_t s1a = *(const ushort8_t*)spn;
        ushort8_t s1b = *(const ushort8_t*)(spn + 8);
        // exp from already-resident regs -> lP; overlaps V DMA, no S wait
        {
            ushort8_t o8;
            for (int e = 0; e < 8; e++) {
                float pe = __expf(bf2f(s0a[e]) - m);
                psum += pe;
                o8[e] = f2bf(pe);
            }
            *(ushort8_t*)(&lP[pr * 64 + ((pc ^ (pr & 7)) * 8)]) = o8;
            for (int e = 0; e < 8; e++) {
                float pe = __expf(bf2f(s0b[e]) - m);
                psum += pe;
                o8[e] = f2bf(pe);
            }
            *(ushort8_t*)(&lP[pr * 64 + (((pc + 1) ^ (pr & 7)) * 8)]) = o8;
        }
        __syncthreads();   // drains vmcnt(0) + LDS writes
        for (int ks = 0; ks < 2; ks++) {
            short8_t af[2], bfr[8];
            for (int mi = 0; mi < 2; mi++) {
                int row = wr * 32 + mi * 16 + lr;
                int ch = ((ks * 4 + lg) ^ (row & 7)) * 8;
                af[mi] = *(const short8_t*)(&lP[row * 64 + ch]);
            }
            for (int ni = 0; ni < 8; ni++) {
                int row = wc * 128 + ni * 16 + lr;
                int ch = ((ks * 4 + lg) ^ (row & 7)) * 8;
                bfr[ni] = *(const short8_t*)(&lV[row * 64 + ch]);
            }
            for (int mi = 0; mi < 2; mi++)
                for (int ni = 0; ni < 8; ni++)
                    acc[mi][ni] = __builtin_amdgcn_mfma_f32_16x16x32_bf16(
                        af[mi], bfr[ni], acc[mi][ni], 0, 0, 0);
        }
        s0a = s1a; s0b = s1b;
    }

    // reduce 4 partial sums per row -> li
    psum += __shfl_xor(psum, 1);
    psum += __shfl_xor(psum, 2);
    if ((tid & 3) == 0) li[pr] = 1.0f / psum;
    __syncthreads();

    // epilogue: Y[row][ci] = bf16(acc * 1/l)
    for (int mi = 0; mi < 2; mi++) {
        for (int ni = 0; ni < 8; ni++) {
            int ci = wc * 128 + ni * 16 + lr;
            int rbase = wr * 32 + mi * 16 + lg * 4;
            for (int r = 0; r < 4; r++) {
                int row = rbase + r;
                Yb[(long)row * 256 + ci] = f2bf(acc[mi][ni][r] * li[row]);
            }
        }
    }
}

// -------------------- fused QK^T + G-conv GEMM (shares A=Qh, K=512)
// grid (10, 32, G): bx<8 -> C=S tile (B=Kh_z);  bx>=8 -> C=Gt tile (B=gwb).
// Direct scalar-store epilogue (LDS-transposed variant measured slower).
__global__ __launch_bounds__(256) void gemm_qkg(
    const unsigned short* __restrict__ Qh,
    const unsigned short* __restrict__ Kh,
    const unsigned short* __restrict__ gwb,
    unsigned short* __restrict__ S,
    unsigned short* __restrict__ Gt)
{
    __shared__ unsigned short lA[128 * 64];
    __shared__ unsigned short lB[128 * 64];
    const int tid = threadIdx.x;
    const int wid = tid >> 6, lane = tid & 63;

    unsigned gx = gridDim.x, gy = gridDim.y;
    unsigned nwg = gx * gy * gridDim.z;
    unsigned lin = blockIdx.x + gx * (blockIdx.y + gy * blockIdx.z);
    unsigned l = ((nwg & 7u) == 0u) ? ((lin & 7u) * (nwg >> 3) + (lin >> 3)) : lin;
    unsigned bx = l % gx;
    unsigned rem = l / gx;
    unsigned by = rem % gy;
    unsigned bz = rem / gy;

    const int z = (int)bz;
    const int m0 = (int)by * 128;
    const unsigned short* Ab = Qh + (long)z * 4096 * 512;
    const unsigned short* Bb;
    unsigned short* Cb;
    int n0, ldc;
    if (bx < 8) {
        Bb = Kh + (long)z * 1024 * 512;  n0 = bx * 128;
        Cb = S + (long)z * 4096 * 1024;  ldc = 1024;
    } else {
        Bb = gwb;                         n0 = (bx - 8) * 128;
        Cb = Gt + (long)z * 4096 * 256;   ldc = 256;
    }

    const int wr = wid >> 1, wc = wid & 1;
    const int lr = lane & 15, lg = lane >> 4;
    const int srA = lane >> 3;
    const int scg = (((lane & 7) ^ srA) << 3);

    f32x4 acc[4][4];
    for (int mi = 0; mi < 4; mi++)
        for (int ni = 0; ni < 4; ni++)
            acc[mi][ni] = (f32x4){0.f, 0.f, 0.f, 0.f};

    for (int k0 = 0; k0 < 512; k0 += 64) {
        __syncthreads();
        for (int i = 0; i < 4; i++) {
            int rowbase = i * 32 + wid * 8;
            gll16(Ab + (long)(m0 + rowbase + srA) * 512 + k0 + scg, &lA[rowbase * 64]);
            gll16(Bb + (long)(n0 + rowbase + srA) * 512 + k0 + scg, &lB[rowbase * 64]);
        }
        __syncthreads();
        for (int kk = 0; kk < 2; kk++) {
            short8_t af[4], bfr[4];
            for (int mi = 0; mi < 4; mi++) {
                int row = wr * 64 + mi * 16 + lr;
                int ch = ((kk * 4 + lg) ^ (row & 7)) * 8;
                af[mi] = *(const short8_t*)(&lA[row * 64 + ch]);
            }
            for (int ni = 0; ni < 4; ni++) {
                int row = wc * 64 + ni * 16 + lr;
                int ch = ((kk * 4 + lg) ^ (row & 7)) * 8;
                bfr[ni] = *(const short8_t*)(&lB[row * 64 + ch]);
            }
            for (int mi = 0; mi < 4; mi++)
                for (int ni = 0; ni < 4; ni++)
                    acc[mi][ni] = __builtin_amdgcn_mfma_f32_16x16x32_bf16(
                        af[mi], bfr[ni], acc[mi][ni], 0, 0, 0);
        }
    }

    for (int mi = 0; mi < 4; mi++) {
        for (int ni = 0; ni < 4; ni++) {
            int ncol = n0 + wc * 64 + ni * 16 + lr;
            int mrow = m0 + wr * 64 + mi * 16 + lg * 4;
            for (int r = 0; r < 4; r++) {
                Cb[(long)(mrow + r) * ldc + ncol] = f2bf(acc[mi][ni][r]);
            }
        }
    }
}

// -------------------------------------------------------------------- GEMM
// EPI: 0 f32 store, 1 bf16 store, 2 v*bnA[m]+bnB[m]+Xres f32 store.
template<int EPI>
__global__ __launch_bounds__(256) void gemm_abt(
    const unsigned short* __restrict__ A, int lda, long abstr,
    const unsigned short* __restrict__ B, int ldb, long bbstr,
    void* __restrict__ Cv, int ldc, long cbstr,
    int K,
    const float* __restrict__ bnA, const float* __restrict__ bnB,
    const float* __restrict__ Xres, long xbstr)
{
    __shared__ unsigned short lA[128 * 64];
    __shared__ unsigned short lB[128 * 64];
    const int tid = threadIdx.x;
    const int wid = tid >> 6, lane = tid & 63;

    unsigned gx = gridDim.x, gy = gridDim.y;
    unsigned nwg = gx * gy * gridDim.z;
    unsigned lin = blockIdx.x + gx * (blockIdx.y + gy * blockIdx.z);
    unsigned l = ((nwg & 7u) == 0u) ? ((lin & 7u) * (nwg >> 3) + (lin >> 3)) : lin;
    unsigned bx = l % gx;
    unsigned rem = l / gx;
    unsigned by = rem % gy;
    unsigned bz = rem / gy;

    const int z = (int)bz;
    const int m0 = (int)by * 128, n0 = (int)bx * 128;
    const unsigned short* Ab = A + z * abstr;
    const unsigned short* Bb = B + z * bbstr;
    const int wr = wid >> 1, wc = wid & 1;
    const int lr = lane & 15, lg = lane >> 4;

    const int srA = lane >> 3;
    const int scg = (((lane & 7) ^ srA) << 3);

    f32x4 acc[4][4];
    for (int mi = 0; mi < 4; mi++)
        for (int ni = 0; ni < 4; ni++)
            acc[mi][ni] = (f32x4){0.f, 0.f, 0.f, 0.f};

    for (int k0 = 0; k0 < K; k0 += 64) {
        __syncthreads();
        for (int i = 0; i < 4; i++) {
            int rowbase = i * 32 + wid * 8;
            gll16(Ab + (long)(m0 + rowbase + srA) * lda + k0 + scg, &lA[rowbase * 64]);
            gll16(Bb + (long)(n0 + rowbase + srA) * ldb + k0 + scg, &lB[rowbase * 64]);
        }
        __syncthreads();
        for (int kk = 0; kk < 2; kk++) {
            short8_t af[4], bfr[4];
            for (int mi = 0; mi < 4; mi++) {
                int row = wr * 64 + mi * 16 + lr;
                int ch = ((kk * 4 + lg) ^ (row & 7)) * 8;
                af[mi] = *(const short8_t*)(&lA[row * 64 + ch]);
            }
            for (int ni = 0; ni < 4; ni++) {
                int row = wc * 64 + ni * 16 + lr;
                int ch = ((kk * 4 + lg) ^ (row & 7)) * 8;
                bfr[ni] = *(const short8_t*)(&lB[row * 64 + ch]);
            }
            for (int mi = 0; mi < 4; mi++)
                for (int ni = 0; ni < 4; ni++)
                    acc[mi][ni] = __builtin_amdgcn_mfma_f32_16x16x32_bf16(
                        af[mi], bfr[ni], acc[mi][ni], 0, 0, 0);
        }
    }

    for (int mi = 0; mi < 4; mi++) {
        for (int ni = 0; ni < 4; ni++) {
            int ncol = n0 + wc * 64 + ni * 16 + lr;
            int mrow = m0 + wr * 64 + mi * 16 + lg * 4;
            for (int r = 0; r < 4; r++) {
                int row = mrow + r;
                float v = acc[mi][ni][r];
                long idx = z * cbstr + (long)row * ldc + ncol;
                if (EPI == 0) {
                    ((float*)Cv)[idx] = v;
                } else if (EPI == 1) {
                    ((unsigned short*)Cv)[idx] = f2bf(v);
                } else {
                    float o = v * bnA[row] + bnB[row] + Xres[z * xbstr + (long)row * ldc + ncol];
                    ((float*)Cv)[idx] = o;
                }
            }
        }
    }
}

// fallback if workspace too small (diagnostic: out = x)
__global__ void copy_residual(const float* __restrict__ x, float* __restrict__ out, long n)
{
    for (long i = blockIdx.x * 256ll + threadIdx.x; i < n; i += (long)gridDim.x * 256)
        out[i] = x[i];
}

extern "C" void kernel_launch(void* const* d_in, const int* in_sizes, int n_in,
                              void* d_out, int out_size, void* d_ws, size_t ws_size,
                              hipStream_t stream)
{
    const float* x     = (const float*)d_in[0];
    const float* g_w   = (const float*)d_in[1];
    const float* g_b   = (const float*)d_in[2];
    const float* W_w   = (const float*)d_in[3];
    const float* W_b   = (const float*)d_in[4];
    const float* gamma = (const float*)d_in[5];
    const float* beta  = (const float*)d_in[6];
    const float* mean  = (const float*)d_in[7];
    const float* var   = (const float*)d_in[8];
    float* out = (float*)d_out;

    char* ws = (char*)d_ws;
    size_t o = 0;
    auto alloc = [&](size_t bytes) { size_t r = o; o = (o + bytes + 255) & ~(size_t)255; return r; };
    size_t o_gwb = alloc(256 * 512 * 2);
    size_t o_wwb = alloc(512 * 256 * 2);
    size_t o_bnA = alloc(512 * 4);
    size_t o_bnB = alloc(512 * 4);
    size_t o_q   = alloc(8ull * 4096 * 512 * 2);   // Qh bf16
    size_t o_k   = alloc(8ull * 1024 * 512 * 2);   // Kh bf16
    size_t o_gp  = alloc(8ull * 256 * 1024 * 2);   // V^T (pooled g, bf16)
    size_t o_y   = alloc(8ull * 4096 * 256 * 2);   // Y (also holds Gt before pooling)
    size_t o_s   = o;                               // S bf16 logits
    const size_t srow_bytes = 1024ull * 2;          // one S row (bf16)
    const size_t sb1 = 4096ull * srow_bytes;        // one batch of S (8 MB)

    int G = 0, RC = 0;
    if      (o_s + 8 * sb1 <= ws_size) G = 8;
    else if (o_s + 4 * sb1 <= ws_size) G = 4;
    else if (o_s + 2 * sb1 <= ws_size) G = 2;
    else if (o_s + 1 * sb1 <= ws_size) G = 1;
    else {
        for (int rc = 2048; rc >= 128; rc >>= 1)
            if (o_s + (size_t)rc * srow_bytes <= ws_size) { RC = rc; break; }
        if (!RC) {
            copy_residual<<<dim3(2048), dim3(256), 0, stream>>>(x, out, (long)out_size);
            return;
        }
    }

    unsigned short* gwb = (unsigned short*)(ws + o_gwb);
    unsigned short* wwb = (unsigned short*)(ws + o_wwb);
    float* bnA = (float*)(ws + o_bnA);
    float* bnB = (float*)(ws + o_bnB);
    unsigned short* Qh  = (unsigned short*)(ws + o_q);
    unsigned short* Kh  = (unsigned short*)(ws + o_k);
    unsigned short* Gp  = (unsigned short*)(ws + o_gp);
    unsigned short* Y   = (unsigned short*)(ws + o_y);
    unsigned short* S   = (unsigned short*)(ws + o_s);

    prep_w<<<dim3(512), dim3(256), 0, stream>>>(g_w, W_w, W_b, gamma, beta, mean, var,
                                                gwb, wwb, bnA, bnB);
    build_qk<<<dim3(32, 16, 8), dim3(256), 0, stream>>>(x, Qh, Kh);

    if (G) {
        for (int bg = 0; bg < 8; bg += G) {
            // fused QK^T + G-conv (shared A panels): S and Gt (into Y slot)
            gemm_qkg<<<dim3(10, 32, G), dim3(256), 0, stream>>>(
                Qh + (size_t)bg * 4096 * 512,
                Kh + (size_t)bg * 1024 * 512,
                gwb,
                S,
                Y + (size_t)bg * 4096 * 256);
            build_v<<<dim3(32, 32, G), dim3(256), 0, stream>>>(
                Y + (size_t)bg * 4096 * 256, g_b, Gp + (size_t)bg * 256 * 1024);
            // fused scan + softmax + PV (deferred normalization)
            pv_fused<<<dim3(64, G), dim3(256), 0, stream>>>(
                S, 4096l * 1024,
                Gp + (size_t)bg * 256 * 1024, 256l * 1024,
                Y + (size_t)bg * 4096 * 256, 4096l * 256);
        }
    } else {
        // Row-chunked path (small workspace): separate G-conv first, then chunks.
        gemm_abt<1><<<dim3(2, 32, 8), dim3(256), 0, stream>>>(
            Qh, 512, 4096l * 512,
            gwb, 512, 0,
            (void*)Y, 256, 4096l * 256, 512,
            nullptr, nullptr, nullptr, 0);
        build_v<<<dim3(32, 32, 8), dim3(256), 0, stream>>>(Y, g_b, Gp);
        for (int b = 0; b < 8; b++) {
            for (int r0 = 0; r0 < 4096; r0 += RC) {
                const unsigned short* Aq = Qh + (size_t)b * 4096 * 512 + (size_t)r0 * 512;
                gemm_abt<1><<<dim3(8, RC / 128, 1), dim3(256), 0, stream>>>(
                    Aq, 512, 0,
                    Kh + (size_t)b * 1024 * 512, 512, 0,
                    (void*)S, 1024, 0, 512,
                    nullptr, nullptr, nullptr, 0);
                pv_fused<<<dim3(RC / 64, 1), dim3(256), 0, stream>>>(
                    S, 0,
                    Gp + (size_t)b * 256 * 1024, 0,
                    Y + ((size_t)b * 4096 + r0) * 256, 0);
            }
        }
    }

    // W-conv + BN + residual: out[b][o][p] = (wwb·Y^T)*bnA[o]+bnB[o]+x  (M=512,N=4096,K=256)
    gemm_abt<2><<<dim3(32, 4, 8), dim3(256), 0, stream>>>(
        wwb, 256, 0,
        Y, 256, 4096l * 256,
        (void*)out, 4096, 512l * 4096, 256,
        bnA, bnB, x, 512l * 4096);
}